// Round 1
// baseline (363.208 us; speedup 1.0000x reference)
//
#include <hip/hip_runtime.h>

#define J 2048
#define BATCH 32768
#define K_ITERS 8   // 8 float4 loads per lane per row: 8*4*64 = 2048 = J

__global__ __launch_bounds__(256)
void QuantumEmbedding_50964081935097_kernel(const float* __restrict__ x,
                                            const float* __restrict__ W,   // [J,2]
                                            const float* __restrict__ P,   // [J]
                                            float* __restrict__ out)       // [BATCH,2]
{
    const int lane = threadIdx.x & 63;
    const int wave_in_block = threadIdx.x >> 6;
    const int wave_id = blockIdx.x * 4 + wave_in_block;
    const int n_waves = gridDim.x * 4;

    // Preload this lane's per-j constants into registers (reused for every row).
    // lane's j set: j0 = k*256 + lane*4, j0..j0+3
    const float inv2pi = 0.15915494309189535f;
    float4 ph[K_ITERS];
    float4 w_a[K_ITERS];   // {W[j0,0],W[j0,1],W[j0+1,0],W[j0+1,1]}
    float4 w_b[K_ITERS];   // {W[j0+2,0],W[j0+2,1],W[j0+3,0],W[j0+3,1]}
#pragma unroll
    for (int k = 0; k < K_ITERS; ++k) {
        const int j0 = k * 256 + lane * 4;
        float4 p = *(const float4*)(P + j0);
        ph[k] = make_float4(p.x * inv2pi, p.y * inv2pi, p.z * inv2pi, p.w * inv2pi);
        w_a[k] = *(const float4*)(W + j0 * 2);
        w_b[k] = *(const float4*)(W + j0 * 2 + 4);
    }

    for (int row = wave_id; row < BATCH; row += n_waves) {
        const float* xr = x + (size_t)row * J;
        float acc0 = 0.f, acc1 = 0.f;
#pragma unroll
        for (int k = 0; k < K_ITERS; ++k) {
            const int j0 = k * 256 + lane * 4;
            float4 xv = *(const float4*)(xr + j0);
            // v_cos_f32 computes cos(2*pi*s); phases pre-scaled by 1/(2*pi)
            float c0 = __builtin_amdgcn_cosf(xv.x * ph[k].x);
            float c1 = __builtin_amdgcn_cosf(xv.y * ph[k].y);
            float c2 = __builtin_amdgcn_cosf(xv.z * ph[k].z);
            float c3 = __builtin_amdgcn_cosf(xv.w * ph[k].w);
            acc0 += c0 * w_a[k].x + c1 * w_a[k].z + c2 * w_b[k].x + c3 * w_b[k].z;
            acc1 += c0 * w_a[k].y + c1 * w_a[k].w + c2 * w_b[k].y + c3 * w_b[k].w;
        }
        // 64-lane butterfly reduction of (acc0, acc1)
#pragma unroll
        for (int off = 32; off > 0; off >>= 1) {
            acc0 += __shfl_down(acc0, off, 64);
            acc1 += __shfl_down(acc1, off, 64);
        }
        if (lane == 0) {
            *(float2*)(out + (size_t)row * 2) = make_float2(acc0, acc1);
        }
    }
}

extern "C" void kernel_launch(void* const* d_in, const int* in_sizes, int n_in,
                              void* d_out, int out_size, void* d_ws, size_t ws_size,
                              hipStream_t stream) {
    const float* x = (const float*)d_in[0];
    const float* W = (const float*)d_in[1];
    const float* P = (const float*)d_in[2];
    float* out = (float*)d_out;

    // 2048 blocks x 4 waves = 8192 waves; each wave handles 4 rows grid-stride.
    dim3 grid(2048), block(256);
    hipLaunchKernelGGL(QuantumEmbedding_50964081935097_kernel, grid, block, 0, stream,
                       x, W, P, out);
}

// Round 3
// 357.418 us; speedup vs baseline: 1.0162x; 1.0162x over previous
//
#include <hip/hip_runtime.h>

#define J 2048
#define BATCH 32768

typedef float vfloat4 __attribute__((ext_vector_type(4)));  // nontemporal-compatible

// 8 rows per wave, 8 lanes per row.
// lane = 8*t + row_in_group; at step k, lane reads x[base+row][k*32 + t*4 .. +3]
// -> per instruction: 8 rows x 128 B contiguous segments, fully-consumed lines.
__global__ __launch_bounds__(256)
void QuantumEmbedding_50964081935097_kernel(const float* __restrict__ x,
                                            const float* __restrict__ W,   // [J,2]
                                            const float* __restrict__ P,   // [J]
                                            float* __restrict__ out)       // [BATCH,2]
{
    const int lane = threadIdx.x & 63;
    const int wave = blockIdx.x * 4 + (threadIdx.x >> 6);
    const int row_in_group = lane & 7;
    const int t = lane >> 3;
    const int base_row = wave * 8;
    if (base_row >= BATCH) return;

    const float inv2pi = 0.15915494309189535f;
    const float* xr = x + (size_t)(base_row + row_in_group) * J;

    float acc0 = 0.f, acc1 = 0.f;

#pragma unroll 4
    for (int k = 0; k < 64; ++k) {
        const int col = k * 32 + t * 4;
        // streaming x: nontemporal so it doesn't evict the 24 KB P/W set from L1
        vfloat4 xv = __builtin_nontemporal_load(
            reinterpret_cast<const vfloat4*>(xr + col));
        float4 pv = *reinterpret_cast<const float4*>(P + col);
        float4 w01 = *reinterpret_cast<const float4*>(W + col * 2);      // W[col..col+1][0..1]
        float4 w23 = *reinterpret_cast<const float4*>(W + col * 2 + 4);  // W[col+2..col+3][0..1]

        // v_cos_f32 takes revolutions: cos(theta) = v_cos(theta / 2pi)
        float c0 = __builtin_amdgcn_cosf(xv.x * (pv.x * inv2pi));
        float c1 = __builtin_amdgcn_cosf(xv.y * (pv.y * inv2pi));
        float c2 = __builtin_amdgcn_cosf(xv.z * (pv.z * inv2pi));
        float c3 = __builtin_amdgcn_cosf(xv.w * (pv.w * inv2pi));

        acc0 += c0 * w01.x + c1 * w01.z + c2 * w23.x + c3 * w23.z;
        acc1 += c0 * w01.y + c1 * w01.w + c2 * w23.y + c3 * w23.w;
    }

    // reduce across t (lanes l, l+8, ..., l+56): 3-step butterfly
    acc0 += __shfl_down(acc0, 32, 64);
    acc1 += __shfl_down(acc1, 32, 64);
    acc0 += __shfl_down(acc0, 16, 64);
    acc1 += __shfl_down(acc1, 16, 64);
    acc0 += __shfl_down(acc0, 8, 64);
    acc1 += __shfl_down(acc1, 8, 64);

    if (lane < 8) {
        // lanes 0..7 hold rows base_row+0..7 -> 64 B contiguous store
        *reinterpret_cast<float2*>(out + (size_t)(base_row + lane) * 2) =
            make_float2(acc0, acc1);
    }
}

extern "C" void kernel_launch(void* const* d_in, const int* in_sizes, int n_in,
                              void* d_out, int out_size, void* d_ws, size_t ws_size,
                              hipStream_t stream) {
    const float* x = (const float*)d_in[0];
    const float* W = (const float*)d_in[1];
    const float* P = (const float*)d_in[2];
    float* out = (float*)d_out;

    // 32768 rows / 8 rows-per-wave = 4096 waves = 1024 blocks x 4 waves.
    dim3 grid(1024), block(256);
    hipLaunchKernelGGL(QuantumEmbedding_50964081935097_kernel, grid, block, 0, stream,
                       x, W, P, out);
}

// Round 4
// 355.515 us; speedup vs baseline: 1.0216x; 1.0054x over previous
//
#include <hip/hip_runtime.h>

#define J 2048
#define BATCH 32768

typedef float vfloat4 __attribute__((ext_vector_type(4)));  // nontemporal-compatible

// 4 rows per wave, 16 lanes per row -> 8192 waves = 32 waves/CU (full slots).
// lane = t*4 + r; at step k, lane reads x[base+r][k*64 + t*4 .. +3]
// -> per instruction: 4 rows x 256 B contiguous segments, fully-consumed lines.
__global__ __launch_bounds__(256)
void QuantumEmbedding_50964081935097_kernel(const float* __restrict__ x,
                                            const float* __restrict__ W,   // [J,2]
                                            const float* __restrict__ P,   // [J]
                                            float* __restrict__ out)       // [BATCH,2]
{
    const int lane = threadIdx.x & 63;
    const int wave = blockIdx.x * 4 + (threadIdx.x >> 6);
    const int r = lane & 3;        // row within group
    const int t = lane >> 2;       // column-chunk index, 0..15
    const int base_row = wave * 4;

    const float inv2pi = 0.15915494309189535f;
    const float* xr = x + (size_t)(base_row + r) * J;

    float acc0 = 0.f, acc1 = 0.f;

#pragma unroll 4
    for (int k = 0; k < 32; ++k) {
        const int col = k * 64 + t * 4;
        // streaming x: nontemporal so it doesn't evict the 24 KB P/W set from L1
        vfloat4 xv = __builtin_nontemporal_load(
            reinterpret_cast<const vfloat4*>(xr + col));
        float4 pv = *reinterpret_cast<const float4*>(P + col);
        float4 w01 = *reinterpret_cast<const float4*>(W + col * 2);      // W[col..col+1][0..1]
        float4 w23 = *reinterpret_cast<const float4*>(W + col * 2 + 4);  // W[col+2..col+3][0..1]

        // v_cos_f32 takes revolutions: cos(theta) = v_cos(theta / 2pi)
        float c0 = __builtin_amdgcn_cosf(xv.x * (pv.x * inv2pi));
        float c1 = __builtin_amdgcn_cosf(xv.y * (pv.y * inv2pi));
        float c2 = __builtin_amdgcn_cosf(xv.z * (pv.z * inv2pi));
        float c3 = __builtin_amdgcn_cosf(xv.w * (pv.w * inv2pi));

        acc0 += c0 * w01.x + c1 * w01.z + c2 * w23.x + c3 * w23.z;
        acc1 += c0 * w01.y + c1 * w01.w + c2 * w23.y + c3 * w23.w;
    }

    // reduce across t (16 lanes per row, stride 4): 4-step butterfly
    acc0 += __shfl_down(acc0, 32, 64);
    acc1 += __shfl_down(acc1, 32, 64);
    acc0 += __shfl_down(acc0, 16, 64);
    acc1 += __shfl_down(acc1, 16, 64);
    acc0 += __shfl_down(acc0, 8, 64);
    acc1 += __shfl_down(acc1, 8, 64);
    acc0 += __shfl_down(acc0, 4, 64);
    acc1 += __shfl_down(acc1, 4, 64);

    if (lane < 4) {
        // lanes 0..3 hold rows base_row+0..3 -> 32 B contiguous store
        *reinterpret_cast<float2*>(out + (size_t)(base_row + lane) * 2) =
            make_float2(acc0, acc1);
    }
}

extern "C" void kernel_launch(void* const* d_in, const int* in_sizes, int n_in,
                              void* d_out, int out_size, void* d_ws, size_t ws_size,
                              hipStream_t stream) {
    const float* x = (const float*)d_in[0];
    const float* W = (const float*)d_in[1];
    const float* P = (const float*)d_in[2];
    float* out = (float*)d_out;

    // 32768 rows / 4 rows-per-wave = 8192 waves = 2048 blocks x 4 waves
    // -> 32 waves/CU across 256 CUs (100% wave slots).
    dim3 grid(2048), block(256);
    hipLaunchKernelGGL(QuantumEmbedding_50964081935097_kernel, grid, block, 0, stream,
                       x, W, P, out);
}